// Round 4
// baseline (182.651 us; speedup 1.0000x reference)
//
#include <hip/hip_runtime.h>

// Problem constants (fixed by reference)
#define GS    256
#define PARAM 128
#define KC    32
#define I1    64
#define I2    32
#define PK    96        // PARAM - KC
#define B_    4
#define NROWS (B_ * GS) // 1024
#define EPS   1e-3f
#define KDIV_INV (1.0f / 16.0f)
#define CHUNK 32
#define VYP   132       // padded vy row stride (floats): 16B-aligned, kills bank conflicts

// Single fused kernel: one block per (b,x) row.
//  - folds BN1/2/3 into scales/shifts per block (cheap)
//  - computes u'_x = (val_x@(M1top-M1bot))*s1 + c1 cooperatively
//  - compacts the sparse mask row (density ~1/16)
//  - recomputes W_y = val_y@M1bot ONLY for active y's (16x less than dense,
//    done in-block so there is no second kernel / no cross-kernel dependency)
//  - tiny MLP L2/L3 on active pairs, masked accumulate, clip, store.
__global__ __launch_bounds__(256, 4) void glmlp_fused(
    const float* __restrict__ mat, const float* __restrict__ val,
    const float* __restrict__ M1, const float* __restrict__ B1,
    const float* __restrict__ M2, const float* __restrict__ B2,
    const float* __restrict__ M3, const float* __restrict__ B3,
    const float* __restrict__ g1, const float* __restrict__ b1,
    const float* __restrict__ m1, const float* __restrict__ v1,
    const float* __restrict__ g2, const float* __restrict__ b2,
    const float* __restrict__ m2, const float* __restrict__ v2,
    const float* __restrict__ g3, const float* __restrict__ b3,
    const float* __restrict__ m3, const float* __restrict__ v3,
    float* __restrict__ out)
{
    __shared__ float vrow[PARAM];        // 0.5 KB
    __shared__ float uxs[I1];
    __shared__ float s1s[I1];
    __shared__ float m2s[I1 * I2];       // 8 KB
    __shared__ float c2s[I2];
    __shared__ float vy[CHUNK][VYP];     // 16.5 KB
    __shared__ float H1[CHUNK][I1];      // 8 KB (first 1 KB aliased as red[4][64])
    __shared__ float H2[CHUNK][I2];      // 4 KB
    __shared__ int   acty[GS];           // 1 KB
    __shared__ float partial[2][PK];
    __shared__ int   cnt;
    // total ~39 KB -> 4 blocks/CU

    float (&red)[4][I1] = *reinterpret_cast<float (*)[4][I1]>(&H1[0][0]);

    const int r = blockIdx.x;
    const int t = threadIdx.x;
    const int wbase = r & ~(GS - 1);     // b * GS

    if (t == 0) cnt = 0;
    if (t < PARAM) vrow[t] = val[r * PARAM + t];
    const float mv = mat[r * GS + t];

    // Layer-3 per-thread setup: t < 192 -> (half h, output k); M3 column + c3 in regs
    const bool l3 = (t < 2 * PK);
    const int k = t % PK;
    const int h = t / PK;
    float m3col[I2];
    float c3k = 0.0f;
    if (l3) {
        const float s3 = g3[k] * rsqrtf(v3[k] + EPS);
        c3k = (B3[k] - m3[k]) * s3 + b3[k];
        #pragma unroll
        for (int ii = 0; ii < I2; ++ii) m3col[ii] = M3[ii * PK + k] * s3;
    }

    // BN2-folded M2 into LDS
    for (int idx = t; idx < I1 * I2; idx += 256) {
        const int j = idx & (I2 - 1);
        m2s[idx] = M2[idx] * g2[j] * rsqrtf(v2[j] + EPS);
    }
    if (t < I2) {
        const float s2 = g2[t] * rsqrtf(v2[t] + EPS);
        c2s[t] = (B2[t] - m2[t]) * s2 + b2[t];
    }
    __syncthreads();   // vrow, cnt, m2s, c2s ready

    // compact mask row (values are exactly 0.0/1.0)
    if (mv != 0.0f) acty[atomicAdd(&cnt, 1)] = t;

    // exact copy: con = val[:, :, :KC]
    if (t < KC) out[r * PARAM + t] = vrow[t];

    // u-phase: 64 i-lanes x 4 quarter-dots. q=0,1 -> T (M1 top); q=2,3 -> Wx (M1 bot)
    {
        const int i = t & (I1 - 1);
        const int q = t >> 6;
        const float* __restrict__ Mb = M1 + ((q >> 1) ? (PARAM * I1) : 0);
        const int p0 = (q & 1) * 64;
        float acc = 0.f;
        #pragma unroll 8
        for (int p = 0; p < 64; ++p)
            acc = fmaf(vrow[p0 + p], Mb[(p0 + p) * I1 + i], acc);
        red[q][i] = acc;
    }
    __syncthreads();   // red + acty/cnt ready
    const int n = cnt;

    if (t < I1) {
        const float s1 = g1[t] * rsqrtf(v1[t] + EPS);
        const float c1 = (B1[t] - m1[t]) * s1 + b1[t];
        s1s[t] = s1;
        uxs[t] = (red[0][t] + red[1][t] - red[2][t] - red[3][t]) * s1 + c1;
    }
    __syncthreads();   // uxs, s1s ready; H1 (alias red) free from here

    const float* __restrict__ M1b = M1 + PARAM * I1;
    float accO = 0.0f;

    for (int base = 0; base < n; base += CHUNK) {
        const int nc = min(CHUNK, n - base);

        // stage active val_y rows into LDS (float4, padded rows)
        for (int idx = t; idx < nc * (PARAM / 4); idx += 256) {
            const int yy = idx >> 5;          // PARAM/4 == 32
            const int pq = idx & 31;
            const float4 v4 =
                ((const float4*)&val[(wbase + acty[base + yy]) * PARAM])[pq];
            *(float4*)&vy[yy][pq * 4] = v4;
        }
        __syncthreads();

        // W_y + layer 1: thread (g = t>>6, i = t&63) handles yy = g + 4*j, j=0..7.
        // M1b value register-cached (8 reuses); vy read as wave-broadcast float4.
        {
            const int i = t & (I1 - 1);
            const int g = t >> 6;
            const float s1 = s1s[i];
            const float ux = uxs[i];
            float acc[8] = {0.f, 0.f, 0.f, 0.f, 0.f, 0.f, 0.f, 0.f};
            for (int p = 0; p < PARAM; p += 4) {
                const float w0 = M1b[(p + 0) * I1 + i];
                const float w1 = M1b[(p + 1) * I1 + i];
                const float w2 = M1b[(p + 2) * I1 + i];
                const float w3 = M1b[(p + 3) * I1 + i];
                #pragma unroll
                for (int j = 0; j < 8; ++j) {
                    const float4 vv = *(const float4*)&vy[g + 4 * j][p];
                    acc[j] = fmaf(vv.x, w0, acc[j]);
                    acc[j] = fmaf(vv.y, w1, acc[j]);
                    acc[j] = fmaf(vv.z, w2, acc[j]);
                    acc[j] = fmaf(vv.w, w3, acc[j]);
                }
            }
            #pragma unroll
            for (int j = 0; j < 8; ++j) {
                const int yy = g + 4 * j;
                if (yy < nc) H1[yy][i] = fmaxf(ux + acc[j] * s1, 0.f);
            }
        }
        __syncthreads();

        // Layer 2: H2[p][j] = relu(H1[p] . M2f[:,j] + c2[j])
        for (int idx = t; idx < nc * I2; idx += 256) {
            const int p = idx >> 5, j = idx & (I2 - 1);
            float a = c2s[j];
            const float4* h1p4 = (const float4*)&H1[p][0];
            #pragma unroll
            for (int i4 = 0; i4 < I1 / 4; ++i4) {
                const float4 hv = h1p4[i4];
                const int i = i4 * 4;
                a = fmaf(hv.x, m2s[(i + 0) * I2 + j], a);
                a = fmaf(hv.y, m2s[(i + 1) * I2 + j], a);
                a = fmaf(hv.z, m2s[(i + 2) * I2 + j], a);
                a = fmaf(hv.w, m2s[(i + 3) * I2 + j], a);
            }
            H2[p][j] = fmaxf(a, 0.f);
        }
        __syncthreads();

        // Layer 3: half h handles pairs p = h, h+2, ...; dual interleaved chains.
        if (l3) {
            int p = h;
            for (; p + 2 < nc; p += 4) {
                float a0 = c3k, a1 = c3k;
                const float4* A4 = (const float4*)&H2[p][0];
                const float4* B4 = (const float4*)&H2[p + 2][0];
                #pragma unroll
                for (int i4 = 0; i4 < I2 / 4; ++i4) {
                    const float4 ha = A4[i4];
                    const float4 hb = B4[i4];
                    const int i = i4 * 4;
                    a0 = fmaf(ha.x, m3col[i + 0], a0);
                    a1 = fmaf(hb.x, m3col[i + 0], a1);
                    a0 = fmaf(ha.y, m3col[i + 1], a0);
                    a1 = fmaf(hb.y, m3col[i + 1], a1);
                    a0 = fmaf(ha.z, m3col[i + 2], a0);
                    a1 = fmaf(hb.z, m3col[i + 2], a1);
                    a0 = fmaf(ha.w, m3col[i + 3], a0);
                    a1 = fmaf(hb.w, m3col[i + 3], a1);
                }
                accO += fmaxf(a0, 0.f) + fmaxf(a1, 0.f);
            }
            for (; p < nc; p += 2) {
                float a0 = c3k;
                const float4* A4 = (const float4*)&H2[p][0];
                #pragma unroll
                for (int i4 = 0; i4 < I2 / 4; ++i4) {
                    const float4 ha = A4[i4];
                    const int i = i4 * 4;
                    a0 = fmaf(ha.x, m3col[i + 0], a0);
                    a0 = fmaf(ha.y, m3col[i + 1], a0);
                    a0 = fmaf(ha.z, m3col[i + 2], a0);
                    a0 = fmaf(ha.w, m3col[i + 3], a0);
                }
                accO += fmaxf(a0, 0.f);
            }
        }
        // no trailing barrier: next iter's barriers fence all cross-phase reuse
    }

    if (l3) partial[h][k] = accO;
    __syncthreads();

    if (t < PK) {
        float v = (partial[0][t] + partial[1][t]) * KDIV_INV;
        v = fminf(fmaxf(v, -1.0f), 1.0f);
        out[r * PARAM + KC + t] = v;
    }
}

extern "C" void kernel_launch(void* const* d_in, const int* in_sizes, int n_in,
                              void* d_out, int out_size, void* d_ws, size_t ws_size,
                              hipStream_t stream) {
    const float* mat = (const float*)d_in[0];
    const float* val = (const float*)d_in[1];
    const float* M1  = (const float*)d_in[2];
    const float* B1  = (const float*)d_in[3];
    const float* M2  = (const float*)d_in[4];
    const float* B2  = (const float*)d_in[5];
    const float* M3  = (const float*)d_in[6];
    const float* B3  = (const float*)d_in[7];
    const float* g1  = (const float*)d_in[8];
    const float* b1  = (const float*)d_in[9];
    const float* m1  = (const float*)d_in[10];
    const float* v1  = (const float*)d_in[11];
    const float* g2  = (const float*)d_in[12];
    const float* b2  = (const float*)d_in[13];
    const float* m2  = (const float*)d_in[14];
    const float* v2  = (const float*)d_in[15];
    const float* g3  = (const float*)d_in[16];
    const float* b3  = (const float*)d_in[17];
    const float* m3  = (const float*)d_in[18];
    const float* v3  = (const float*)d_in[19];

    float* out = (float*)d_out;

    hipLaunchKernelGGL(glmlp_fused, dim3(NROWS), dim3(256), 0, stream,
                       mat, val, M1, B1, M2, B2, M3, B3,
                       g1, b1, m1, v1, g2, b2, m2, v2, g3, b3, m3, v3,
                       out);
}

// Round 5
// 153.824 us; speedup vs baseline: 1.1874x; 1.1874x over previous
//
#include <hip/hip_runtime.h>

// Problem constants (fixed by reference)
#define GS    256
#define PARAM 128
#define KC    32
#define I1    64
#define I2    32
#define PK    96        // PARAM - KC
#define B_    4
#define NROWS (B_ * GS) // 1024
#define EPS   1e-3f
#define KDIV_INV (1.0f / 16.0f)
#define CHUNK 32
#define VYP   132       // padded vy row stride (floats): 16B-aligned, kills bank conflicts

// Single fused kernel: one block per (b,x) row.
// NOTE: __launch_bounds__(256) with NO min-waves arg. R4's (256,4) capped the
// allocator at 128 VGPRs -> m3col[32]+acc[8] spilled to scratch -> 220 MB of
// HBM spill traffic (WRITE_SIZE 145 MB) and 2.2x regression. This kernel
// wants ~150 VGPRs; let it have them.
__global__ __launch_bounds__(256) void glmlp_fused(
    const float* __restrict__ mat, const float* __restrict__ val,
    const float* __restrict__ M1, const float* __restrict__ B1,
    const float* __restrict__ M2, const float* __restrict__ B2,
    const float* __restrict__ M3, const float* __restrict__ B3,
    const float* __restrict__ g1, const float* __restrict__ b1,
    const float* __restrict__ m1, const float* __restrict__ v1,
    const float* __restrict__ g2, const float* __restrict__ b2,
    const float* __restrict__ m2, const float* __restrict__ v2,
    const float* __restrict__ g3, const float* __restrict__ b3,
    const float* __restrict__ m3, const float* __restrict__ v3,
    float* __restrict__ out)
{
    __shared__ float vrow[PARAM];        // 0.5 KB
    __shared__ float uxs[I1];
    __shared__ float s1s[I1];
    __shared__ float m2s[I1 * I2];       // 8 KB
    __shared__ float c2s[I2];
    __shared__ float vy[CHUNK][VYP];     // 16.5 KB
    __shared__ float H1[CHUNK][I1];      // 8 KB (first 1 KB aliased as red[4][64])
    __shared__ float H2[CHUNK][I2];      // 4 KB
    __shared__ int   acty[GS];           // 1 KB
    __shared__ float partial[2][PK];
    __shared__ int   cnt;
    // total ~39 KB

    float (&red)[4][I1] = *reinterpret_cast<float (*)[4][I1]>(&H1[0][0]);

    const int r = blockIdx.x;
    const int t = threadIdx.x;
    const int wbase = r & ~(GS - 1);     // b * GS

    if (t == 0) cnt = 0;
    if (t < PARAM) vrow[t] = val[r * PARAM + t];
    const float mv = mat[r * GS + t];

    // Layer-3 per-thread setup: t < 192 -> (half h, output k); M3 column + c3 in regs
    const bool l3 = (t < 2 * PK);
    const int k = t % PK;
    const int h = t / PK;
    float m3col[I2];
    float c3k = 0.0f;
    if (l3) {
        const float s3 = g3[k] * rsqrtf(v3[k] + EPS);
        c3k = (B3[k] - m3[k]) * s3 + b3[k];
        #pragma unroll
        for (int ii = 0; ii < I2; ++ii) m3col[ii] = M3[ii * PK + k] * s3;
    }

    // BN2-folded M2 into LDS
    for (int idx = t; idx < I1 * I2; idx += 256) {
        const int j = idx & (I2 - 1);
        m2s[idx] = M2[idx] * g2[j] * rsqrtf(v2[j] + EPS);
    }
    if (t < I2) {
        const float s2 = g2[t] * rsqrtf(v2[t] + EPS);
        c2s[t] = (B2[t] - m2[t]) * s2 + b2[t];
    }
    __syncthreads();   // vrow, cnt, m2s, c2s ready

    // compact mask row (values are exactly 0.0/1.0)
    if (mv != 0.0f) acty[atomicAdd(&cnt, 1)] = t;

    // exact copy: con = val[:, :, :KC]
    if (t < KC) out[r * PARAM + t] = vrow[t];

    // u-phase: 64 i-lanes x 4 quarter-dots. q=0,1 -> T (M1 top); q=2,3 -> Wx (M1 bot)
    {
        const int i = t & (I1 - 1);
        const int q = t >> 6;
        const float* __restrict__ Mb = M1 + ((q >> 1) ? (PARAM * I1) : 0);
        const int p0 = (q & 1) * 64;
        float acc = 0.f;
        #pragma unroll 8
        for (int p = 0; p < 64; ++p)
            acc = fmaf(vrow[p0 + p], Mb[(p0 + p) * I1 + i], acc);
        red[q][i] = acc;
    }
    __syncthreads();   // red + acty/cnt ready
    const int n = cnt;

    if (t < I1) {
        const float s1 = g1[t] * rsqrtf(v1[t] + EPS);
        const float c1 = (B1[t] - m1[t]) * s1 + b1[t];
        s1s[t] = s1;
        uxs[t] = (red[0][t] + red[1][t] - red[2][t] - red[3][t]) * s1 + c1;
    }
    __syncthreads();   // uxs, s1s ready; H1 (alias red) free from here

    const float* __restrict__ M1b = M1 + PARAM * I1;
    float accO = 0.0f;

    for (int base = 0; base < n; base += CHUNK) {
        const int nc = min(CHUNK, n - base);

        // stage active val_y rows into LDS (float4, padded rows)
        for (int idx = t; idx < nc * (PARAM / 4); idx += 256) {
            const int yy = idx >> 5;          // PARAM/4 == 32
            const int pq = idx & 31;
            const float4 v4 =
                ((const float4*)&val[(wbase + acty[base + yy]) * PARAM])[pq];
            *(float4*)&vy[yy][pq * 4] = v4;
        }
        __syncthreads();

        // W_y + layer 1: thread (g = t>>6, i = t&63) handles yy = g + 4*j, j=0..7.
        // M1b value register-cached (8 reuses); vy read as wave-broadcast float4.
        {
            const int i = t & (I1 - 1);
            const int g = t >> 6;
            const float s1 = s1s[i];
            const float ux = uxs[i];
            float acc[8] = {0.f, 0.f, 0.f, 0.f, 0.f, 0.f, 0.f, 0.f};
            for (int p = 0; p < PARAM; p += 4) {
                const float w0 = M1b[(p + 0) * I1 + i];
                const float w1 = M1b[(p + 1) * I1 + i];
                const float w2 = M1b[(p + 2) * I1 + i];
                const float w3 = M1b[(p + 3) * I1 + i];
                #pragma unroll
                for (int j = 0; j < 8; ++j) {
                    const float4 vv = *(const float4*)&vy[g + 4 * j][p];
                    acc[j] = fmaf(vv.x, w0, acc[j]);
                    acc[j] = fmaf(vv.y, w1, acc[j]);
                    acc[j] = fmaf(vv.z, w2, acc[j]);
                    acc[j] = fmaf(vv.w, w3, acc[j]);
                }
            }
            #pragma unroll
            for (int j = 0; j < 8; ++j) {
                const int yy = g + 4 * j;
                if (yy < nc) H1[yy][i] = fmaxf(ux + acc[j] * s1, 0.f);
            }
        }
        __syncthreads();

        // Layer 2: H2[p][j] = relu(H1[p] . M2f[:,j] + c2[j])
        for (int idx = t; idx < nc * I2; idx += 256) {
            const int p = idx >> 5, j = idx & (I2 - 1);
            float a = c2s[j];
            const float4* h1p4 = (const float4*)&H1[p][0];
            #pragma unroll
            for (int i4 = 0; i4 < I1 / 4; ++i4) {
                const float4 hv = h1p4[i4];
                const int i = i4 * 4;
                a = fmaf(hv.x, m2s[(i + 0) * I2 + j], a);
                a = fmaf(hv.y, m2s[(i + 1) * I2 + j], a);
                a = fmaf(hv.z, m2s[(i + 2) * I2 + j], a);
                a = fmaf(hv.w, m2s[(i + 3) * I2 + j], a);
            }
            H2[p][j] = fmaxf(a, 0.f);
        }
        __syncthreads();

        // Layer 3: half h handles pairs p = h, h+2, ...; dual interleaved chains.
        if (l3) {
            int p = h;
            for (; p + 2 < nc; p += 4) {
                float a0 = c3k, a1 = c3k;
                const float4* A4 = (const float4*)&H2[p][0];
                const float4* B4 = (const float4*)&H2[p + 2][0];
                #pragma unroll
                for (int i4 = 0; i4 < I2 / 4; ++i4) {
                    const float4 ha = A4[i4];
                    const float4 hb = B4[i4];
                    const int i = i4 * 4;
                    a0 = fmaf(ha.x, m3col[i + 0], a0);
                    a1 = fmaf(hb.x, m3col[i + 0], a1);
                    a0 = fmaf(ha.y, m3col[i + 1], a0);
                    a1 = fmaf(hb.y, m3col[i + 1], a1);
                    a0 = fmaf(ha.z, m3col[i + 2], a0);
                    a1 = fmaf(hb.z, m3col[i + 2], a1);
                    a0 = fmaf(ha.w, m3col[i + 3], a0);
                    a1 = fmaf(hb.w, m3col[i + 3], a1);
                }
                accO += fmaxf(a0, 0.f) + fmaxf(a1, 0.f);
            }
            for (; p < nc; p += 2) {
                float a0 = c3k;
                const float4* A4 = (const float4*)&H2[p][0];
                #pragma unroll
                for (int i4 = 0; i4 < I2 / 4; ++i4) {
                    const float4 ha = A4[i4];
                    const int i = i4 * 4;
                    a0 = fmaf(ha.x, m3col[i + 0], a0);
                    a0 = fmaf(ha.y, m3col[i + 1], a0);
                    a0 = fmaf(ha.z, m3col[i + 2], a0);
                    a0 = fmaf(ha.w, m3col[i + 3], a0);
                }
                accO += fmaxf(a0, 0.f);
            }
        }
        // no trailing barrier: next iter's barriers fence all cross-phase reuse
    }

    if (l3) partial[h][k] = accO;
    __syncthreads();

    if (t < PK) {
        float v = (partial[0][t] + partial[1][t]) * KDIV_INV;
        v = fminf(fmaxf(v, -1.0f), 1.0f);
        out[r * PARAM + KC + t] = v;
    }
}

extern "C" void kernel_launch(void* const* d_in, const int* in_sizes, int n_in,
                              void* d_out, int out_size, void* d_ws, size_t ws_size,
                              hipStream_t stream) {
    const float* mat = (const float*)d_in[0];
    const float* val = (const float*)d_in[1];
    const float* M1  = (const float*)d_in[2];
    const float* B1  = (const float*)d_in[3];
    const float* M2  = (const float*)d_in[4];
    const float* B2  = (const float*)d_in[5];
    const float* M3  = (const float*)d_in[6];
    const float* B3  = (const float*)d_in[7];
    const float* g1  = (const float*)d_in[8];
    const float* b1  = (const float*)d_in[9];
    const float* m1  = (const float*)d_in[10];
    const float* v1  = (const float*)d_in[11];
    const float* g2  = (const float*)d_in[12];
    const float* b2  = (const float*)d_in[13];
    const float* m2  = (const float*)d_in[14];
    const float* v2  = (const float*)d_in[15];
    const float* g3  = (const float*)d_in[16];
    const float* b3  = (const float*)d_in[17];
    const float* m3  = (const float*)d_in[18];
    const float* v3  = (const float*)d_in[19];

    float* out = (float*)d_out;

    hipLaunchKernelGGL(glmlp_fused, dim3(NROWS), dim3(256), 0, stream,
                       mat, val, M1, B1, M2, B2, M3, B3,
                       g1, b1, m1, v1, g2, b2, m2, v2, g3, b3, m3, v3,
                       out);
}

// Round 6
// 129.095 us; speedup vs baseline: 1.4149x; 1.1916x over previous
//
#include <hip/hip_runtime.h>

// Problem constants (fixed by reference)
#define GS    256
#define PARAM 128
#define KC    32
#define I1    64
#define I2    32
#define PK    96        // PARAM - KC
#define B_    4
#define NROWS (B_ * GS) // 1024
#define EPS   1e-3f
#define KDIV_INV (1.0f / 16.0f)
#define CHUNK 32

// Workspace layout (float offsets)
constexpr int U_OFF   = 0;                   // NROWS*I1
constexpr int W_OFF   = NROWS * I1;
constexpr int M2F_OFF = 2 * NROWS * I1;      // I1*I2
constexpr int C2_OFF  = M2F_OFF + I1 * I2;   // I2
constexpr int M3F_OFF = C2_OFF + I2;         // I2*PK
constexpr int C3_OFF  = M3F_OFF + I2 * PK;   // PK
constexpr int C1_OFF  = C3_OFF + PK;         // I1

// Kernel A: one block per row. 256 thr = 64 i-lanes x 4 quarter-dots.
// u = val.(M1top - M1bot) = T - W; compute T and W (1 load per MAC each).
__global__ __launch_bounds__(256) void glmlp_precompute(
    const float* __restrict__ val, const float* __restrict__ M1,
    const float* __restrict__ B1,
    const float* __restrict__ M2, const float* __restrict__ B2,
    const float* __restrict__ M3, const float* __restrict__ B3,
    const float* __restrict__ g1, const float* __restrict__ b1,
    const float* __restrict__ m1, const float* __restrict__ v1,
    const float* __restrict__ g2, const float* __restrict__ b2,
    const float* __restrict__ m2, const float* __restrict__ v2,
    const float* __restrict__ g3, const float* __restrict__ b3,
    const float* __restrict__ m3, const float* __restrict__ v3,
    float* __restrict__ ws, float* __restrict__ out)
{
    const int blk = blockIdx.x;
    const int t = threadIdx.x;

    if (blk < NROWS) {
        __shared__ float vrow[PARAM];
        __shared__ float red[4][I1];
        const int r = blk;
        if (t < PARAM) vrow[t] = val[r * PARAM + t];
        __syncthreads();

        // exact copy: con = val[:, :, :KC]
        if (t < KC) out[r * PARAM + t] = vrow[t];

        const int i = t & (I1 - 1);
        const int q = t >> 6;                         // 0..3
        // q=0,1 -> T (M1 top half); q=2,3 -> W (M1 bottom half)
        const float* __restrict__ Mb = M1 + ((q >> 1) ? (PARAM * I1) : 0);
        const int p0 = (q & 1) * 64;
        float acc = 0.f;
        #pragma unroll 8
        for (int p = 0; p < 64; ++p)
            acc = fmaf(vrow[p0 + p], Mb[(p0 + p) * I1 + i], acc);
        red[q][i] = acc;
        __syncthreads();

        if (q == 0) {
            const float T  = red[0][i] + red[1][i];
            const float Wv = red[2][i] + red[3][i];
            const float s1 = g1[i] * rsqrtf(v1[i] + EPS);
            ws[U_OFF + r * I1 + i] = (T - Wv) * s1;
            ws[W_OFF + r * I1 + i] = Wv * s1;
        }
    } else {
        // BN folding block
        if (t < I1) {
            const float s1 = g1[t] * rsqrtf(v1[t] + EPS);
            ws[C1_OFF + t] = B1[t] * s1 + b1[t] - m1[t] * s1;
        }
        if (t < I2) {
            const float s2 = g2[t] * rsqrtf(v2[t] + EPS);
            ws[C2_OFF + t] = B2[t] * s2 + b2[t] - m2[t] * s2;
        }
        if (t < PK) {
            const float s3 = g3[t] * rsqrtf(v3[t] + EPS);
            ws[C3_OFF + t] = B3[t] * s3 + b3[t] - m3[t] * s3;
        }
        for (int idx = t; idx < I1 * I2; idx += 256) {
            const int j = idx & (I2 - 1);
            const float s2 = g2[j] * rsqrtf(v2[j] + EPS);
            ws[M2F_OFF + idx] = M2[idx] * s2;
        }
        for (int idx = t; idx < I2 * PK; idx += 256) {
            const int k = idx % PK;
            const float s3 = g3[k] * rsqrtf(v3[k] + EPS);
            ws[M3F_OFF + idx] = M3[idx] * s3;
        }
    }
}

// Kernel B: one block per (b,x) row. All folded weights in LDS (no per-thread
// arrays -> VGPR < 128 -> 4 blocks/CU, +33% TLP vs R3's 148-VGPR version).
// Dual-chain L3 kept; m3 read from LDS stride-1 (conflict-free).
__global__ __launch_bounds__(256) void glmlp_pairs(
    const float* __restrict__ mat, const float* __restrict__ ws,
    float* __restrict__ out)
{
    __shared__ float m2s[I1 * I2];      // 8 KB
    __shared__ float m3s[I2 * PK];      // 12 KB
    __shared__ float uxs[I1];
    __shared__ float c2s[I2];
    __shared__ float c3s[PK];
    __shared__ float H1[CHUNK][I1];     // 8 KB
    __shared__ float H2[CHUNK][I2];     // 4 KB
    __shared__ int   acty[GS];          // 1 KB
    __shared__ float partial[2][PK];
    __shared__ int   cnt;
    // ~34.6 KB -> 4 blocks/CU (LDS-limited) provided VGPR <= 128

    const int r = blockIdx.x;
    const int t = threadIdx.x;
    const int wbase = r & ~(GS - 1);     // b * GS (w vectors indexed by global row)
    const float* __restrict__ W = ws + W_OFF;

    if (t == 0) cnt = 0;
    const float mv = mat[r * GS + t];
    for (int idx = t; idx < I1 * I2; idx += 256) m2s[idx] = ws[M2F_OFF + idx];
    for (int idx = t; idx < I2 * PK; idx += 256) m3s[idx] = ws[M3F_OFF + idx];
    if (t < I2) c2s[t] = ws[C2_OFF + t];
    if (t < PK) c3s[t] = ws[C3_OFF + t];
    if (t < I1) uxs[t] = ws[U_OFF + r * I1 + t] + ws[C1_OFF + t];
    __syncthreads();   // cnt zeroed, stages landed

    // compact the mask row (values are exactly 0.0/1.0)
    if (mv != 0.0f) acty[atomicAdd(&cnt, 1)] = t;
    __syncthreads();
    const int n = cnt;

    const bool l3 = (t < 2 * PK);
    const int k = t % PK;
    const int h = t / PK;
    float accO = 0.0f;

    for (int base = 0; base < n; base += CHUNK) {
        const int nc = min(CHUNK, n - base);

        // Layer 1: H1[p][i] = relu(u'_x[i] + w'_y[i])  (c1 folded into uxs)
        for (int idx = t; idx < nc * I1; idx += 256) {
            const int p = idx >> 6, i = idx & (I1 - 1);
            const int y = acty[base + p];
            H1[p][i] = fmaxf(uxs[i] + W[(wbase + y) * I1 + i], 0.0f);
        }
        __syncthreads();

        // Layer 2: H2[p][j] = relu(H1[p] . M2f[:,j] + c2[j])
        for (int idx = t; idx < nc * I2; idx += 256) {
            const int p = idx >> 5, j = idx & (I2 - 1);
            float a = c2s[j];
            const float4* h1p4 = (const float4*)&H1[p][0];
            #pragma unroll
            for (int i4 = 0; i4 < I1 / 4; ++i4) {
                const float4 hv = h1p4[i4];
                const int i = i4 * 4;
                a = fmaf(hv.x, m2s[(i + 0) * I2 + j], a);
                a = fmaf(hv.y, m2s[(i + 1) * I2 + j], a);
                a = fmaf(hv.z, m2s[(i + 2) * I2 + j], a);
                a = fmaf(hv.w, m2s[(i + 3) * I2 + j], a);
            }
            H2[p][j] = fmaxf(a, 0.0f);
        }
        __syncthreads();

        // Layer 3: half h handles pairs p = h, h+2, ...; dual interleaved chains.
        if (l3) {
            int p = h;
            for (; p + 2 < nc; p += 4) {
                float a0 = c3s[k], a1 = c3s[k];
                const float4* A4 = (const float4*)&H2[p][0];
                const float4* B4 = (const float4*)&H2[p + 2][0];
                #pragma unroll
                for (int i4 = 0; i4 < I2 / 4; ++i4) {
                    const float4 ha = A4[i4];
                    const float4 hb = B4[i4];
                    const int i = i4 * 4;
                    const float w0 = m3s[(i + 0) * PK + k];
                    const float w1 = m3s[(i + 1) * PK + k];
                    const float w2 = m3s[(i + 2) * PK + k];
                    const float w3 = m3s[(i + 3) * PK + k];
                    a0 = fmaf(ha.x, w0, a0);
                    a1 = fmaf(hb.x, w0, a1);
                    a0 = fmaf(ha.y, w1, a0);
                    a1 = fmaf(hb.y, w1, a1);
                    a0 = fmaf(ha.z, w2, a0);
                    a1 = fmaf(hb.z, w2, a1);
                    a0 = fmaf(ha.w, w3, a0);
                    a1 = fmaf(hb.w, w3, a1);
                }
                accO += fmaxf(a0, 0.0f) + fmaxf(a1, 0.0f);
            }
            for (; p < nc; p += 2) {
                float a0 = c3s[k];
                const float4* A4 = (const float4*)&H2[p][0];
                #pragma unroll
                for (int i4 = 0; i4 < I2 / 4; ++i4) {
                    const float4 ha = A4[i4];
                    const int i = i4 * 4;
                    a0 = fmaf(ha.x, m3s[(i + 0) * PK + k], a0);
                    a0 = fmaf(ha.y, m3s[(i + 1) * PK + k], a0);
                    a0 = fmaf(ha.z, m3s[(i + 2) * PK + k], a0);
                    a0 = fmaf(ha.w, m3s[(i + 3) * PK + k], a0);
                }
                accO += fmaxf(a0, 0.0f);
            }
        }
        // no trailing barrier: next iter's post-L1 barrier fences H2 reuse
    }

    if (l3) partial[h][k] = accO;
    __syncthreads();

    if (t < PK) {
        float v = (partial[0][t] + partial[1][t]) * KDIV_INV;
        v = fminf(fmaxf(v, -1.0f), 1.0f);
        out[r * PARAM + KC + t] = v;
    }
}

extern "C" void kernel_launch(void* const* d_in, const int* in_sizes, int n_in,
                              void* d_out, int out_size, void* d_ws, size_t ws_size,
                              hipStream_t stream) {
    const float* mat = (const float*)d_in[0];
    const float* val = (const float*)d_in[1];
    const float* M1  = (const float*)d_in[2];
    const float* B1  = (const float*)d_in[3];
    const float* M2  = (const float*)d_in[4];
    const float* B2  = (const float*)d_in[5];
    const float* M3  = (const float*)d_in[6];
    const float* B3  = (const float*)d_in[7];
    const float* g1  = (const float*)d_in[8];
    const float* b1  = (const float*)d_in[9];
    const float* m1  = (const float*)d_in[10];
    const float* v1  = (const float*)d_in[11];
    const float* g2  = (const float*)d_in[12];
    const float* b2  = (const float*)d_in[13];
    const float* m2  = (const float*)d_in[14];
    const float* v2  = (const float*)d_in[15];
    const float* g3  = (const float*)d_in[16];
    const float* b3  = (const float*)d_in[17];
    const float* m3  = (const float*)d_in[18];
    const float* v3  = (const float*)d_in[19];

    float* ws  = (float*)d_ws;
    float* out = (float*)d_out;

    hipLaunchKernelGGL(glmlp_precompute, dim3(NROWS + 1), dim3(256), 0, stream,
                       val, M1, B1, M2, B2, M3, B3,
                       g1, b1, m1, v1, g2, b2, m2, v2, g3, b3, m3, v3,
                       ws, out);

    hipLaunchKernelGGL(glmlp_pairs, dim3(NROWS), dim3(256), 0, stream,
                       mat, ws, out);
}

// Round 7
// 122.674 us; speedup vs baseline: 1.4889x; 1.0523x over previous
//
#include <hip/hip_runtime.h>

// Problem constants (fixed by reference)
#define GS    256
#define PARAM 128
#define KC    32
#define I1    64
#define I2    32
#define PK    96        // PARAM - KC
#define B_    4
#define NROWS (B_ * GS) // 1024
#define EPS   1e-3f
#define KDIV_INV (1.0f / 16.0f)

// Workspace layout (float offsets)
constexpr int U_OFF   = 0;                   // NROWS*I1
constexpr int W_OFF   = NROWS * I1;
constexpr int M2F_OFF = 2 * NROWS * I1;      // I1*I2
constexpr int C2_OFF  = M2F_OFF + I1 * I2;   // I2
constexpr int M3F_OFF = C2_OFF + I2;         // I2*PK
constexpr int C3_OFF  = M3F_OFF + I2 * PK;   // PK
constexpr int C1_OFF  = C3_OFF + PK;         // I1

// Kernel A: one block per row. 256 thr = 64 i-lanes x 4 quarter-dots.
// u = val.(M1top - M1bot) = T - W; compute T and W (1 load per MAC each).
__global__ __launch_bounds__(256) void glmlp_precompute(
    const float* __restrict__ val, const float* __restrict__ M1,
    const float* __restrict__ B1,
    const float* __restrict__ M2, const float* __restrict__ B2,
    const float* __restrict__ M3, const float* __restrict__ B3,
    const float* __restrict__ g1, const float* __restrict__ b1,
    const float* __restrict__ m1, const float* __restrict__ v1,
    const float* __restrict__ g2, const float* __restrict__ b2,
    const float* __restrict__ m2, const float* __restrict__ v2,
    const float* __restrict__ g3, const float* __restrict__ b3,
    const float* __restrict__ m3, const float* __restrict__ v3,
    float* __restrict__ ws, float* __restrict__ out)
{
    const int blk = blockIdx.x;
    const int t = threadIdx.x;

    if (blk < NROWS) {
        __shared__ float vrow[PARAM];
        __shared__ float red[4][I1];
        const int r = blk;
        if (t < PARAM) vrow[t] = val[r * PARAM + t];
        // exact copy: con = val[:, :, :KC] (direct from global; no barrier dep)
        if (t < KC) out[r * PARAM + t] = val[r * PARAM + t];
        __syncthreads();

        const int i = t & (I1 - 1);
        const int q = t >> 6;                         // 0..3
        // q=0,1 -> T (M1 top half); q=2,3 -> W (M1 bottom half)
        const float* __restrict__ Mb = M1 + ((q >> 1) ? (PARAM * I1) : 0);
        const int p0 = (q & 1) * 64;
        float aa = 0.f, bb = 0.f;                     // dual chains (dep 32)
        #pragma unroll 8
        for (int p = 0; p < 64; p += 2) {
            aa = fmaf(vrow[p0 + p],     Mb[(p0 + p) * I1 + i],     aa);
            bb = fmaf(vrow[p0 + p + 1], Mb[(p0 + p + 1) * I1 + i], bb);
        }
        red[q][i] = aa + bb;
        __syncthreads();

        if (q == 0) {
            const float T  = red[0][i] + red[1][i];
            const float Wv = red[2][i] + red[3][i];
            const float s1 = g1[i] * rsqrtf(v1[i] + EPS);
            ws[U_OFF + r * I1 + i] = (T - Wv) * s1;
            ws[W_OFF + r * I1 + i] = Wv * s1;
        }
    } else {
        // BN folding block
        if (t < I1) {
            const float s1 = g1[t] * rsqrtf(v1[t] + EPS);
            ws[C1_OFF + t] = B1[t] * s1 + b1[t] - m1[t] * s1;
        }
        if (t < I2) {
            const float s2 = g2[t] * rsqrtf(v2[t] + EPS);
            ws[C2_OFF + t] = B2[t] * s2 + b2[t] - m2[t] * s2;
        }
        if (t < PK) {
            const float s3 = g3[t] * rsqrtf(v3[t] + EPS);
            ws[C3_OFF + t] = B3[t] * s3 + b3[t] - m3[t] * s3;
        }
        for (int idx = t; idx < I1 * I2; idx += 256) {
            const int j = idx & (I2 - 1);
            const float s2 = g2[j] * rsqrtf(v2[j] + EPS);
            ws[M2F_OFF + idx] = M2[idx] * s2;
        }
        for (int idx = t; idx < I2 * PK; idx += 256) {
            const int k = idx % PK;
            const float s3 = g3[k] * rsqrtf(v3[k] + EPS);
            ws[M3F_OFF + idx] = M3[idx] * s3;
        }
    }
}

// Kernel B: one block per (b,x) row; 4 waves. Each WAVE owns pairs p = w mod 4
// end-to-end with NO in-loop barriers: H1 lives in registers (lane i = channel
// i), all transposes via __shfl (ds_bpermute, wave-safe). Only 2 barriers per
// block total. LDS ~24 KB -> 6 blocks/CU; waves progress independently.
__global__ __launch_bounds__(256) void glmlp_pairs(
    const float* __restrict__ mat, const float* __restrict__ ws,
    float* __restrict__ out)
{
    __shared__ float m2s[I1 * I2];      // 8 KB   [p*32 + j]
    __shared__ float m3s[I2 * PK];      // 12 KB  [i*96 + k]
    __shared__ float uxs[I1];
    __shared__ float c2s[I2];
    __shared__ float c3s[PK];
    __shared__ float partial[4][PK];    // 1.5 KB
    __shared__ int   acty[GS];          // 1 KB
    __shared__ int   cnt;

    const int r = blockIdx.x;
    const int t = threadIdx.x;
    const int lane = t & 63;
    const int w = t >> 6;               // wave id 0..3
    const int jj = lane & 31;
    const int p0 = (lane >> 5) * 32;    // this lane's L2 half-range base
    const int wbase = r & ~(GS - 1);    // b * GS
    const float* __restrict__ W = ws + W_OFF;

    if (t == 0) cnt = 0;
    const float mv = mat[r * GS + t];
    for (int idx = t; idx < I1 * I2; idx += 256) m2s[idx] = ws[M2F_OFF + idx];
    for (int idx = t; idx < I2 * PK; idx += 256) m3s[idx] = ws[M3F_OFF + idx];
    if (t < I2) c2s[t] = ws[C2_OFF + t];
    if (t < PK) c3s[t] = ws[C3_OFF + t];
    if (t < I1) uxs[t] = ws[U_OFF + r * I1 + t] + ws[C1_OFF + t];
    __syncthreads();

    // compact the mask row (values are exactly 0.0/1.0)
    if (mv != 0.0f) acty[atomicAdd(&cnt, 1)] = t;
    __syncthreads();
    const int n = cnt;

    // per-lane constants
    const float ux   = uxs[lane];       // layer-1 channel for this lane
    const float c2j  = c2s[jj];
    const float c3_0 = c3s[lane];       // output k0 = lane (0..63)
    const float c3_1 = c3s[64 + jj];    // output k1 = 64 + jj (duplicated across halves)

    float acc0 = 0.f, acc1 = 0.f;

    int p = w;
    float wv = (p < n) ? W[(wbase + acty[p]) * I1 + lane] : 0.f;
    while (p < n) {
        const int pn = p + 4;
        const float wvn = (pn < n) ? W[(wbase + acty[pn]) * I1 + lane] : 0.f;

        // Layer 1 (in register): H1[lane] for this pair
        const float h1 = fmaxf(ux + wv, 0.f);

        // Layer 2: lane computes half-dot for column jj over p-range [p0, p0+32)
        float a = 0.f, b = 0.f;
        #pragma unroll
        for (int s = 0; s < 32; s += 2) {
            a = fmaf(__shfl(h1, p0 + s),     m2s[(p0 + s) * I2 + jj],     a);
            b = fmaf(__shfl(h1, p0 + s + 1), m2s[(p0 + s + 1) * I2 + jj], b);
        }
        const float ab = a + b;
        // combine halves: every lane gets the full dot for column jj
        const float h2 = fmaxf(__shfl(ab, jj) + __shfl(ab, 32 + jj) + c2j, 0.f);
        // now lane L holds H2[jj] (columns duplicated across the two halves;
        // lane i (i<32) holds H2[i] - used as the broadcast source below)

        // Layer 3: outputs k0 = lane, k1 = 64 + jj; dual chains per output
        float d0a = c3_0, d0b = 0.f, d1a = c3_1, d1b = 0.f;
        #pragma unroll
        for (int i = 0; i < I2; i += 2) {
            const float he = __shfl(h2, i);
            const float ho = __shfl(h2, i + 1);
            d0a = fmaf(he, m3s[i * PK + lane], d0a);
            d0b = fmaf(ho, m3s[(i + 1) * PK + lane], d0b);
            d1a = fmaf(he, m3s[i * PK + 64 + jj], d1a);
            d1b = fmaf(ho, m3s[(i + 1) * PK + 64 + jj], d1b);
        }
        acc0 += fmaxf(d0a + d0b, 0.f);
        acc1 += fmaxf(d1a + d1b, 0.f);

        wv = wvn;
        p = pn;
    }

    partial[w][lane] = acc0;
    if (lane < 32) partial[w][64 + lane] = acc1;   // halves hold identical acc1
    __syncthreads();

    if (t < PK) {
        float v = (partial[0][t] + partial[1][t] + partial[2][t] + partial[3][t])
                  * KDIV_INV;
        v = fminf(fmaxf(v, -1.0f), 1.0f);
        out[r * PARAM + KC + t] = v;
    }
}

extern "C" void kernel_launch(void* const* d_in, const int* in_sizes, int n_in,
                              void* d_out, int out_size, void* d_ws, size_t ws_size,
                              hipStream_t stream) {
    const float* mat = (const float*)d_in[0];
    const float* val = (const float*)d_in[1];
    const float* M1  = (const float*)d_in[2];
    const float* B1  = (const float*)d_in[3];
    const float* M2  = (const float*)d_in[4];
    const float* B2  = (const float*)d_in[5];
    const float* M3  = (const float*)d_in[6];
    const float* B3  = (const float*)d_in[7];
    const float* g1  = (const float*)d_in[8];
    const float* b1  = (const float*)d_in[9];
    const float* m1  = (const float*)d_in[10];
    const float* v1  = (const float*)d_in[11];
    const float* g2  = (const float*)d_in[12];
    const float* b2  = (const float*)d_in[13];
    const float* m2  = (const float*)d_in[14];
    const float* v2  = (const float*)d_in[15];
    const float* g3  = (const float*)d_in[16];
    const float* b3  = (const float*)d_in[17];
    const float* m3  = (const float*)d_in[18];
    const float* v3  = (const float*)d_in[19];

    float* ws  = (float*)d_ws;
    float* out = (float*)d_out;

    hipLaunchKernelGGL(glmlp_precompute, dim3(NROWS + 1), dim3(256), 0, stream,
                       val, M1, B1, M2, B2, M3, B3,
                       g1, b1, m1, v1, g2, b2, m2, v2, g3, b3, m3, v3,
                       ws, out);

    hipLaunchKernelGGL(glmlp_pairs, dim3(NROWS), dim3(256), 0, stream,
                       mat, ws, out);
}

// Round 8
// 109.754 us; speedup vs baseline: 1.6642x; 1.1177x over previous
//
#include <hip/hip_runtime.h>

// Problem constants (fixed by reference)
#define GS    256
#define PARAM 128
#define KC    32
#define I1    64
#define I2    32
#define PK    96        // PARAM - KC
#define B_    4
#define NROWS (B_ * GS) // 1024
#define EPS   1e-3f
#define KDIV_INV (1.0f / 16.0f)

// Workspace layout (float offsets)
constexpr int U_OFF   = 0;                   // NROWS*I1
constexpr int W_OFF   = NROWS * I1;
constexpr int M2F_OFF = 2 * NROWS * I1;      // I1*I2
constexpr int C2_OFF  = M2F_OFF + I1 * I2;   // I2
constexpr int M3F_OFF = C2_OFF + I2;         // I2*PK
constexpr int C3_OFF  = M3F_OFF + I2 * PK;   // PK
constexpr int C1_OFF  = C3_OFF + PK;         // I1

__device__ __forceinline__ float rdlane(float v, int l) {
    return __uint_as_float(__builtin_amdgcn_readlane(__float_as_uint(v), l));
}

// Kernel A: one block per row. 256 thr = 64 i-lanes x 4 quarter-dots.
// u = val.(M1top - M1bot) = T - W; compute T and W (1 load per MAC each).
__global__ __launch_bounds__(256) void glmlp_precompute(
    const float* __restrict__ val, const float* __restrict__ M1,
    const float* __restrict__ B1,
    const float* __restrict__ M2, const float* __restrict__ B2,
    const float* __restrict__ M3, const float* __restrict__ B3,
    const float* __restrict__ g1, const float* __restrict__ b1,
    const float* __restrict__ m1, const float* __restrict__ v1,
    const float* __restrict__ g2, const float* __restrict__ b2,
    const float* __restrict__ m2, const float* __restrict__ v2,
    const float* __restrict__ g3, const float* __restrict__ b3,
    const float* __restrict__ m3, const float* __restrict__ v3,
    float* __restrict__ ws, float* __restrict__ out)
{
    const int blk = blockIdx.x;
    const int t = threadIdx.x;

    if (blk < NROWS) {
        __shared__ float vrow[PARAM];
        __shared__ float red[4][I1];
        const int r = blk;
        if (t < PARAM) vrow[t] = val[r * PARAM + t];
        // exact copy: con = val[:, :, :KC] (direct from global; no barrier dep)
        if (t < KC) out[r * PARAM + t] = val[r * PARAM + t];
        __syncthreads();

        const int i = t & (I1 - 1);
        const int q = t >> 6;                         // 0..3
        // q=0,1 -> T (M1 top half); q=2,3 -> W (M1 bottom half)
        const float* __restrict__ Mb = M1 + ((q >> 1) ? (PARAM * I1) : 0);
        const int p0 = (q & 1) * 64;
        float aa = 0.f, bb = 0.f;                     // dual chains (dep 32)
        #pragma unroll 8
        for (int p = 0; p < 64; p += 2) {
            aa = fmaf(vrow[p0 + p],     Mb[(p0 + p) * I1 + i],     aa);
            bb = fmaf(vrow[p0 + p + 1], Mb[(p0 + p + 1) * I1 + i], bb);
        }
        red[q][i] = aa + bb;
        __syncthreads();

        if (q == 0) {
            const float T  = red[0][i] + red[1][i];
            const float Wv = red[2][i] + red[3][i];
            const float s1 = g1[i] * rsqrtf(v1[i] + EPS);
            ws[U_OFF + r * I1 + i] = (T - Wv) * s1;
            ws[W_OFF + r * I1 + i] = Wv * s1;
        }
    } else {
        // BN folding block
        if (t < I1) {
            const float s1 = g1[t] * rsqrtf(v1[t] + EPS);
            ws[C1_OFF + t] = B1[t] * s1 + b1[t] - m1[t] * s1;
        }
        if (t < I2) {
            const float s2 = g2[t] * rsqrtf(v2[t] + EPS);
            ws[C2_OFF + t] = B2[t] * s2 + b2[t] - m2[t] * s2;
        }
        if (t < PK) {
            const float s3 = g3[t] * rsqrtf(v3[t] + EPS);
            ws[C3_OFF + t] = B3[t] * s3 + b3[t] - m3[t] * s3;
        }
        for (int idx = t; idx < I1 * I2; idx += 256) {
            const int j = idx & (I2 - 1);
            const float s2 = g2[j] * rsqrtf(v2[j] + EPS);
            ws[M2F_OFF + idx] = M2[idx] * s2;
        }
        for (int idx = t; idx < I2 * PK; idx += 256) {
            const int k = idx % PK;
            const float s3 = g3[k] * rsqrtf(v3[k] + EPS);
            ws[M3F_OFF + idx] = M3[idx] * s3;
        }
    }
}

// Kernel B: one block per (b,x) row; 4 waves; wave w owns pairs p = w mod 4
// end-to-end. All cross-lane broadcasts via v_readlane (wave-uniform index,
// SGPR result -> scalar operand of v_fma): ~1 LDS op per pair vs R7's ~192
// (R7 was LDS-pipe-bound). Weights live in per-lane REGISTERS:
//   lane (h=lane>>5, j=lane&31): m2col[s]=M2f[s][j] (full column, dup across h)
//   m3a[i]=M3f[i][lane] (k=lane), m3b[i]=M3f[i][64+j] (k=64+j, dup across h)
// LDS ~2.6 KB; 2 barriers total.
__global__ __launch_bounds__(256) void glmlp_pairs(
    const float* __restrict__ mat, const float* __restrict__ ws,
    float* __restrict__ out)
{
    __shared__ int   acty[GS];          // 1 KB
    __shared__ float partial[4][PK];    // 1.5 KB
    __shared__ int   cnt;

    const int r = blockIdx.x;
    const int t = threadIdx.x;
    const int lane = t & 63;
    const int w = t >> 6;               // wave id 0..3
    const int jj = lane & 31;
    const int wbase = r & ~(GS - 1);    // b * GS
    const float* __restrict__ W = ws + W_OFF;

    if (t == 0) cnt = 0;
    const float mv = mat[r * GS + t];

    // register-resident folded weights (coalesced L2-hit loads, once per block)
    float m2col[I1];                    // 64 VGPR
    #pragma unroll
    for (int s = 0; s < I1; ++s)
        m2col[s] = ws[M2F_OFF + s * I2 + jj];
    float m3a[I2], m3b[I2];             // 64 VGPR
    #pragma unroll
    for (int i = 0; i < I2; ++i) {
        m3a[i] = ws[M3F_OFF + i * PK + lane];
        m3b[i] = ws[M3F_OFF + i * PK + 64 + jj];
    }
    const float ux  = ws[U_OFF + r * I1 + lane] + ws[C1_OFF + lane];
    const float c2j = ws[C2_OFF + jj];
    const float c30 = ws[C3_OFF + lane];
    const float c31 = ws[C3_OFF + 64 + jj];

    __syncthreads();                    // cnt=0 visible
    // compact the mask row (values are exactly 0.0/1.0)
    if (mv != 0.0f) acty[atomicAdd(&cnt, 1)] = t;
    __syncthreads();
    const int n = cnt;

    float acc0 = 0.f, acc1 = 0.f;

    int p = w;
    float wv = (p < n) ? W[(wbase + acty[p]) * I1 + lane] : 0.f;
    while (p < n) {
        const int pn = p + 4;
        const float wvn = (pn < n) ? W[(wbase + acty[pn]) * I1 + lane] : 0.f;

        // Layer 1 (register): lane holds H1[lane]
        const float h1 = fmaxf(ux + wv, 0.f);

        // Layer 2: every lane computes the FULL dot for its column jj via
        // 64 uniform readlane broadcasts; 4 interleaved chains (dep 16).
        float a0 = 0.f, a1 = 0.f, a2 = 0.f, a3 = 0.f;
        #pragma unroll
        for (int s = 0; s < I1; s += 4) {
            a0 = fmaf(rdlane(h1, s + 0), m2col[s + 0], a0);
            a1 = fmaf(rdlane(h1, s + 1), m2col[s + 1], a1);
            a2 = fmaf(rdlane(h1, s + 2), m2col[s + 2], a2);
            a3 = fmaf(rdlane(h1, s + 3), m2col[s + 3], a3);
        }
        // lane l now holds H2[l & 31] (duplicated across halves)
        const float h2 = fmaxf((a0 + a1) + (a2 + a3) + c2j, 0.f);

        // Layer 3: 32 uniform broadcasts of H2[i] (lane i holds H2[i], i<32);
        // each serves both output columns k0=lane, k1=64+jj. Dual chains each.
        float d0a = c30, d0b = 0.f, d1a = c31, d1b = 0.f;
        #pragma unroll
        for (int i = 0; i < I2; i += 2) {
            const float he = rdlane(h2, i);
            const float ho = rdlane(h2, i + 1);
            d0a = fmaf(he, m3a[i],     d0a);
            d0b = fmaf(ho, m3a[i + 1], d0b);
            d1a = fmaf(he, m3b[i],     d1a);
            d1b = fmaf(ho, m3b[i + 1], d1b);
        }
        acc0 += fmaxf(d0a + d0b, 0.f);
        acc1 += fmaxf(d1a + d1b, 0.f);

        wv = wvn;
        p = pn;
    }

    partial[w][lane] = acc0;
    if (lane < 32) partial[w][64 + lane] = acc1;   // halves hold identical acc1
    __syncthreads();

    if (t < PK) {
        float v = (partial[0][t] + partial[1][t] + partial[2][t] + partial[3][t])
                  * KDIV_INV;
        v = fminf(fmaxf(v, -1.0f), 1.0f);
        out[r * PARAM + KC + t] = v;
    }
}

extern "C" void kernel_launch(void* const* d_in, const int* in_sizes, int n_in,
                              void* d_out, int out_size, void* d_ws, size_t ws_size,
                              hipStream_t stream) {
    const float* mat = (const float*)d_in[0];
    const float* val = (const float*)d_in[1];
    const float* M1  = (const float*)d_in[2];
    const float* B1  = (const float*)d_in[3];
    const float* M2  = (const float*)d_in[4];
    const float* B2  = (const float*)d_in[5];
    const float* M3  = (const float*)d_in[6];
    const float* B3  = (const float*)d_in[7];
    const float* g1  = (const float*)d_in[8];
    const float* b1  = (const float*)d_in[9];
    const float* m1  = (const float*)d_in[10];
    const float* v1  = (const float*)d_in[11];
    const float* g2  = (const float*)d_in[12];
    const float* b2  = (const float*)d_in[13];
    const float* m2  = (const float*)d_in[14];
    const float* v2  = (const float*)d_in[15];
    const float* g3  = (const float*)d_in[16];
    const float* b3  = (const float*)d_in[17];
    const float* m3  = (const float*)d_in[18];
    const float* v3  = (const float*)d_in[19];

    float* ws  = (float*)d_ws;
    float* out = (float*)d_out;

    hipLaunchKernelGGL(glmlp_precompute, dim3(NROWS + 1), dim3(256), 0, stream,
                       val, M1, B1, M2, B2, M3, B3,
                       g1, b1, m1, v1, g2, b2, m2, v2, g3, b3, m3, v3,
                       ws, out);

    hipLaunchKernelGGL(glmlp_pairs, dim3(NROWS), dim3(256), 0, stream,
                       mat, ws, out);
}